// Round 7
// baseline (189.680 us; speedup 1.0000x reference)
//
#include <hip/hip_runtime.h>
#include <hip/hip_bf16.h>
#include <math.h>

// B=4, NB=2048 -> 8192 leaf blocks of L=16 tokens x C=128; H=8 heads x D=16.
// 512 threads/block (8 waves): wave w owns q-tile w, k-tile w, v-tile w (= head w's V),
// head w's attention, and proj cols [w*16, w*16+16). Edge MLP spread over all 512
// threads (two 8-hidden-unit halves -> two partial planes, summed at use).
typedef __attribute__((ext_vector_type(8))) short bf16x8;
typedef __attribute__((ext_vector_type(4))) float f32x4;
typedef __attribute__((ext_vector_type(4))) unsigned short us4;
typedef __attribute__((ext_vector_type(2))) unsigned int u32x2;

struct bfpair { unsigned short hi, lo; };

static __device__ __forceinline__ unsigned short f2bf_rn(float f) {
    union { __hip_bfloat16 h; unsigned short u; } cv;
    cv.h = __float2bfloat16(f);
    return cv.u;
}
static __device__ __forceinline__ float bf2f(unsigned short u) {
    union { unsigned int i; float f; } cv;
    cv.i = ((unsigned int)u) << 16;
    return cv.f;
}
// truncation split: hi = trunc-bf16(f), lo = trunc-bf16(f - hi).
static __device__ __forceinline__ bfpair split2(float f) {
    bfpair p;
    unsigned int u = __float_as_uint(f);
    p.hi = (unsigned short)(u >> 16);
    float r = f - __uint_as_float(u & 0xffff0000u);
    p.lo = (unsigned short)(__float_as_uint(r) >> 16);
    return p;
}
static __device__ __forceinline__ f32x4 MFMA(bf16x8 a, bf16x8 b, f32x4 c) {
    return __builtin_amdgcn_mfma_f32_16x16x32_bf16(a, b, c, 0, 0, 0);
}
static __device__ __forceinline__ float sigmoid_fast(float t) {
    return __builtin_amdgcn_rcpf(1.f + __expf(-t));
}

// ---- prep: Wbig = bf16([Wqkv(384); Wbr(8); zeros(8)]) [400][128]; Wp = bf16(Wproj)
__global__ __launch_bounds__(256) void prep_kernel(
    const float* __restrict__ Wqkv, const float* __restrict__ Wbr,
    const float* __restrict__ Wproj,
    unsigned short* __restrict__ Wbig, unsigned short* __restrict__ Wp)
{
    int i = blockIdx.x * 256 + threadIdx.x;
    if (i < 400 * 128) {
        int n = i >> 7, k = i & 127;
        float v = (n < 384) ? Wqkv[i] : (n < 392 ? Wbr[(n - 384) * 128 + k] : 0.f);
        Wbig[i] = f2bf_rn(v);
    } else {
        int j = i - 400 * 128;
        if (j < 128 * 128) Wp[j] = f2bf_rn(Wproj[j]);
    }
}

__global__ __launch_bounds__(512) void leaf_main(
    const float* __restrict__ x, const int* __restrict__ mask,
    const float* __restrict__ edge,
    const unsigned short* __restrict__ Wbig, const unsigned short* __restrict__ Wp,
    const float* __restrict__ bqkv, const float* __restrict__ bproj,
    const float* __restrict__ eg_w1, const float* __restrict__ eg_b1,
    const float* __restrict__ eg_w2, const float* __restrict__ eg_b2,
    const float* __restrict__ bbr, float* __restrict__ out)
{
    __shared__ unsigned short qhiS[16 * 136], qloS[16 * 136];  // q hi/lo (trunc split)
    __shared__ unsigned short khiS[16 * 136];                  // k rounded bf16
    __shared__ unsigned short vtS[128 * 24];                   // [h*16+d][tok(24 pad)]
    __shared__ unsigned short ewS[2][8 * 256];                 // two partial planes [h][q*16+k]
    __shared__ float logitS[256];                              // [q*16+k]
    __shared__ unsigned short gS[16 * 8];                      // [tok][h] bf16
    __shared__ float vbS[128];                                 // v_blk [h*16+d]
    __shared__ union XU {                                      // x stage aliases P + x_mid
        struct { unsigned short xhi[16 * 128], xlo[16 * 128]; } a;  // 8192 B (phases 0-1)
        struct { unsigned short p[8 * 16 * 24], mhi[16 * 136]; } b; // 10496 B (phases 3-4)
    } xu;
    // total ~39.7 KB -> 4 blocks/CU

    const int bid  = blockIdx.x;
    const int tid  = threadIdx.x;
    const int lane = tid & 63;
    const int wave = tid >> 6;
    const int c15  = lane & 15;
    const int quad = lane >> 4;
    const int pid  = tid & 255;     // edge pair index (both halves)
    const bf16x8 zf = {0, 0, 0, 0, 0, 0, 0, 0};

    // ---- hoisted global loads (all 512 threads; halves share pair pid) ----
    const int    mv = mask[(size_t)bid * 256 + pid];
    const float4 ev = *(const float4*)&edge[((size_t)bid * 256 + pid) * 4];

    // ---- phase 0: stage x (one float4 per thread), trunc split, chunk-XOR swizzle ----
    {
        const float4* xb = (const float4*)(x + (size_t)bid * 2048);
        float4 v = xb[tid];
        int row = tid >> 5, c4 = tid & 31;
        int off = row * 128 + (((c4 >> 1) ^ (row & 7)) << 3) + ((c4 & 1) << 2);
        float f[4] = {v.x, v.y, v.z, v.w};
        us4 hi, lo;
        #pragma unroll
        for (int j = 0; j < 4; ++j) {
            bfpair p = split2(f[j]);
            hi[j] = p.hi;
            lo[j] = p.lo;
        }
        *(us4*)&xu.a.xhi[off] = hi;
        *(us4*)&xu.a.xlo[off] = lo;
    }

    // B prefetch (depth 2): tile0 = q-tile wave, tile1 = k-tile wave
    bf16x8 Bt[2][4];
    const unsigned short* wbase = Wbig + c15 * 128 + quad * 8;
    {
        const unsigned short* w0 = wbase + (wave * 16) * 128;
        #pragma unroll
        for (int kk = 0; kk < 4; ++kk) Bt[0][kk] = *(const bf16x8*)(w0 + kk * 32);
        const unsigned short* w1 = wbase + ((8 + wave) * 16) * 128;
        #pragma unroll
        for (int kk = 0; kk < 4; ++kk) Bt[1][kk] = *(const bf16x8*)(w1 + kk * 32);
    }
    const float bq0 = bqkv[wave * 16 + c15];
    const float bq1 = bqkv[128 + wave * 16 + c15];
    const float bq2 = bqkv[256 + wave * 16 + c15];
    const float bgate = bbr[c15 & 7];

    __syncthreads();   // barrier 1: x staged

    // ---- edge-gate MLP spread over all 512 threads (8 hidden units each) ----
    {
        const int q = pid >> 4, k = pid & 15;
        int s = mv;
        s += __shfl_xor(s, 1); s += __shfl_xor(s, 2);
        s += __shfl_xor(s, 4); s += __shfl_xor(s, 8);
        float m = (float)mv;
        if (q == k && s < 1) m = 1.f;
        float bp0, bp1, bp2, bp3;
        if (q == k) { bp0 = bp1 = bp2 = 0.f; bp3 = 1.f; }
        else        { bp0 = ev.x; bp1 = ev.y; bp2 = ev.z; bp3 = ev.w; }
        if (tid < 256) logitS[tid] = (m == 0.f) ? -INFINITY : bp3;
        const int half = tid >> 8;          // 0: j 0..7 (+eg_b2), 1: j 8..15
        const int jb = half * 8;
        float ew[8];
        #pragma unroll
        for (int h = 0; h < 8; ++h) ew[h] = half ? 0.f : eg_b2[h];
        #pragma unroll
        for (int jj = 0; jj < 8; ++jj) {
            const int j = jb + jj;
            float z = eg_w1[j * 4 + 0] * bp0 + eg_w1[j * 4 + 1] * bp1 +
                      eg_w1[j * 4 + 2] * bp2 + eg_w1[j * 4 + 3] * bp3 + eg_b1[j];
            float g = z * sigmoid_fast(z * (1.5957691216f + 0.071354816f * z * z));
            #pragma unroll
            for (int h = 0; h < 8; ++h) ew[h] += eg_w2[h * 16 + j] * g;
        }
        #pragma unroll
        for (int h = 0; h < 8; ++h)
            ewS[half][h * 256 + pid] = (m == 0.f) ? (unsigned short)0
                                     : (unsigned short)(__float_as_uint(ew[h]) >> 16);
    }

    // ---- A-fragments from LDS (swizzled, conflict-free) ----
    bf16x8 ah[4], al[4];
    #pragma unroll
    for (int kk = 0; kk < 4; ++kk) {
        int off = c15 * 128 + (((kk * 4 + quad) ^ (c15 & 7)) << 3);
        ah[kk] = *(const bf16x8*)&xu.a.xhi[off];
        al[kk] = *(const bf16x8*)&xu.a.xlo[off];
    }

    const int colq = wave * 16 + c15;

    // ---- tile 0: q (hi/lo split) ----
    {
        f32x4 acc = {0.f, 0.f, 0.f, 0.f};
        #pragma unroll
        for (int kk = 0; kk < 4; ++kk) {
            acc = MFMA(ah[kk], Bt[0][kk], acc);
            acc = MFMA(al[kk], Bt[0][kk], acc);
        }
        // prefetch v-tile into slot 0
        const unsigned short* w2 = wbase + ((16 + wave) * 16) * 128;
        #pragma unroll
        for (int kk = 0; kk < 4; ++kk) Bt[0][kk] = *(const bf16x8*)(w2 + kk * 32);
        #pragma unroll
        for (int r = 0; r < 4; ++r) {
            bfpair p = split2(acc[r] + bq0);
            qhiS[(quad * 4 + r) * 136 + colq] = p.hi;
            qloS[(quad * 4 + r) * 136 + colq] = p.lo;
        }
    }

    // ---- tile 1: k (rounded) ----
    {
        f32x4 acc = {0.f, 0.f, 0.f, 0.f};
        #pragma unroll
        for (int kk = 0; kk < 4; ++kk) {
            acc = MFMA(ah[kk], Bt[1][kk], acc);
            acc = MFMA(al[kk], Bt[1][kk], acc);
        }
        if (wave == 7) {   // prefetch gate tile (Wbig rows 384..399) into slot 1
            const unsigned short* w3 = wbase + 384 * 128;
            #pragma unroll
            for (int kk = 0; kk < 4; ++kk) Bt[1][kk] = *(const bf16x8*)(w3 + kk * 32);
        }
        #pragma unroll
        for (int r = 0; r < 4; ++r)
            khiS[(quad * 4 + r) * 136 + colq] = f2bf_rn(acc[r] + bq1);
    }

    // ---- tile 2: v (transposed; block mean via shuffle) ----
    {
        f32x4 acc = {0.f, 0.f, 0.f, 0.f};
        #pragma unroll
        for (int kk = 0; kk < 4; ++kk) {
            acc = MFMA(ah[kk], Bt[0][kk], acc);
            acc = MFMA(al[kk], Bt[0][kk], acc);
        }
        #pragma unroll
        for (int r = 0; r < 4; ++r)
            vtS[colq * 24 + quad * 4 + r] = f2bf_rn(acc[r] + bq2);
        float s = acc[0] + acc[1] + acc[2] + acc[3];
        s += __shfl_xor(s, 16);
        s += __shfl_xor(s, 32);
        if (lane < 16) vbS[colq] = s * 0.0625f + bq2;
    }

    // ---- tile 3: block-node gate (wave 7) ----
    if (wave == 7) {
        f32x4 acc = {0.f, 0.f, 0.f, 0.f};
        #pragma unroll
        for (int kk = 0; kk < 4; ++kk) {
            acc = MFMA(ah[kk], Bt[1][kk], acc);
            acc = MFMA(al[kk], Bt[1][kk], acc);
        }
        if (c15 < 8) {
            #pragma unroll
            for (int r = 0; r < 4; ++r)
                gS[(quad * 4 + r) * 8 + c15] = f2bf_rn(sigmoid_fast(acc[r] + bgate));
        }
    }
    __syncthreads();   // barrier 2: qkv/gate/MLP done; x-stage LDS now dead

    // prefetch proj weights + bias (consumed after barrier 3)
    bf16x8 Wt[4];
    {
        const unsigned short* wp = Wp + (wave * 16 + c15) * 128 + quad * 8;
        #pragma unroll
        for (int kk = 0; kk < 4; ++kk) Wt[kk] = *(const bf16x8*)(wp + kk * 32);
    }
    const float bpv = bproj[wave * 16 + c15];

    // ---- phase 3: attention, swapped QK^T (head h = wave) ----
    {
        const int h = wave;
        const int fo = c15 * 136 + h * 16 + (quad & 1) * 8;
        bf16x8 kh_ = zf, qh_ = zf, ql_ = zf;
        if (quad < 2) {
            kh_ = *(const bf16x8*)&khiS[fo];
            qh_ = *(const bf16x8*)&qhiS[fo];
            ql_ = *(const bf16x8*)&qloS[fo];
        }
        f32x4 sc = {0.f, 0.f, 0.f, 0.f};
        sc = MFMA(kh_, qh_, sc);
        sc = MFMA(kh_, ql_, sc);
        const f32x4 lg = *(const f32x4*)&logitS[c15 * 16 + quad * 4];
        const us4 ea = *(const us4*)&ewS[0][h * 256 + c15 * 16 + quad * 4];
        const us4 eb = *(const us4*)&ewS[1][h * 256 + c15 * 16 + quad * 4];
        float s0 = sc[0] * 0.25f + lg[0];
        float s1 = sc[1] * 0.25f + lg[1];
        float s2 = sc[2] * 0.25f + lg[2];
        float s3 = sc[3] * 0.25f + lg[3];
        float mx = fmaxf(fmaxf(s0, s1), fmaxf(s2, s3));
        mx = fmaxf(mx, __shfl_xor(mx, 16));
        mx = fmaxf(mx, __shfl_xor(mx, 32));
        float e0 = __expf(s0 - mx), e1 = __expf(s1 - mx);
        float e2 = __expf(s2 - mx), e3 = __expf(s3 - mx);
        float sm = (e0 + e1) + (e2 + e3);
        sm += __shfl_xor(sm, 16);
        sm += __shfl_xor(sm, 32);
        const float inv = __builtin_amdgcn_rcpf(sm);
        const float p0 = e0 * inv + bf2f(ea[0]) + bf2f(eb[0]);
        const float p1 = e1 * inv + bf2f(ea[1]) + bf2f(eb[1]);
        const float p2 = e2 * inv + bf2f(ea[2]) + bf2f(eb[2]);
        const float p3 = e3 * inv + bf2f(ea[3]) + bf2f(eb[3]);
        u32x2 pw;
        pw[0] = (unsigned int)f2bf_rn(p0) | ((unsigned int)f2bf_rn(p1) << 16);
        pw[1] = (unsigned int)f2bf_rn(p2) | ((unsigned int)f2bf_rn(p3) << 16);
        *(u32x2*)&xu.b.p[wave * 384 + c15 * 24 + quad * 4] = pw;

        bf16x8 pa = zf, vb = zf;
        if (quad < 2) {
            pa = *(const bf16x8*)&xu.b.p[wave * 384 + c15 * 24 + (quad & 1) * 8];
            vb = *(const bf16x8*)&vtS[(h * 16 + c15) * 24 + (quad & 1) * 8];
        }
        f32x4 xs = {0.f, 0.f, 0.f, 0.f};
        xs = MFMA(pa, vb, xs);
        const float vblk = vbS[h * 16 + c15];
        #pragma unroll
        for (int r = 0; r < 4; ++r) {
            const int tok = quad * 4 + r;
            float val = xs[r] + bf2f(gS[tok * 8 + h]) * vblk;
            xu.b.mhi[tok * 136 + h * 16 + c15] = f2bf_rn(val);
        }
    }
    __syncthreads();   // barrier 3: x_mid ready

    // ---- phase 4: output projection (one 16-col tile per wave) ----
    {
        bf16x8 mh[4];
        #pragma unroll
        for (int kk = 0; kk < 4; ++kk)
            mh[kk] = *(const bf16x8*)&xu.b.mhi[c15 * 136 + kk * 32 + quad * 8];
        f32x4 acc = {0.f, 0.f, 0.f, 0.f};
        #pragma unroll
        for (int kk = 0; kk < 4; ++kk) acc = MFMA(mh[kk], Wt[kk], acc);
        float* op = out + (size_t)bid * 2048;
        #pragma unroll
        for (int r = 0; r < 4; ++r)
            op[(quad * 4 + r) * 128 + wave * 16 + c15] = acc[r] + bpv;
    }
}

extern "C" void kernel_launch(void* const* d_in, const int* in_sizes, int n_in,
                              void* d_out, int out_size, void* d_ws, size_t ws_size,
                              hipStream_t stream) {
    const float* x     = (const float*)d_in[0];
    const int*   amask = (const int*)  d_in[1];
    const float* edge  = (const float*)d_in[2];
    const float* Wqkv  = (const float*)d_in[3];
    const float* bqkv  = (const float*)d_in[4];
    const float* Wproj = (const float*)d_in[5];
    const float* bproj = (const float*)d_in[6];
    const float* eg_w1 = (const float*)d_in[7];
    const float* eg_b1 = (const float*)d_in[8];
    const float* eg_w2 = (const float*)d_in[9];
    const float* eg_b2 = (const float*)d_in[10];
    const float* Wbr   = (const float*)d_in[11];
    const float* bbr   = (const float*)d_in[12];
    float* outp = (float*)d_out;

    unsigned short* Wbig = (unsigned short*)d_ws;                      // 400*128 bf16
    unsigned short* Wp   = (unsigned short*)((char*)d_ws + 400 * 128 * 2);

    hipLaunchKernelGGL(prep_kernel, dim3(264), dim3(256), 0, stream,
                       Wqkv, Wbr, Wproj, Wbig, Wp);
    hipLaunchKernelGGL(leaf_main, dim3(8192), dim3(512), 0, stream,
                       x, amask, edge, Wbig, Wp, bqkv, bproj,
                       eg_w1, eg_b1, eg_w2, eg_b2, bbr, outp);
}

// Round 8
// 161.485 us; speedup vs baseline: 1.1746x; 1.1746x over previous
//
#include <hip/hip_runtime.h>
#include <hip/hip_bf16.h>
#include <math.h>

// B=4, NB=2048 -> 8192 leaf blocks of L=16 tokens x C=128; H=8 heads x D=16.
// 256 threads/block (4 waves), LDS ~25.3KB -> 6 blocks/CU (6 independent chains).
// Wave w owns qkv col-tiles {w, w+4} of each of q/k/v, heads {2w, 2w+1}, and
// proj col-tiles {w, w+4}. Wave 0 also does the block-node gate tile.
typedef __attribute__((ext_vector_type(8))) short bf16x8;
typedef __attribute__((ext_vector_type(4))) float f32x4;
typedef __attribute__((ext_vector_type(4))) unsigned short us4;
typedef __attribute__((ext_vector_type(2))) unsigned int u32x2;

struct bfpair { unsigned short hi, lo; };

static __device__ __forceinline__ unsigned short f2bf_rn(float f) {
    union { __hip_bfloat16 h; unsigned short u; } cv;
    cv.h = __float2bfloat16(f);
    return cv.u;
}
static __device__ __forceinline__ float bf2f(unsigned short u) {
    union { unsigned int i; float f; } cv;
    cv.i = ((unsigned int)u) << 16;
    return cv.f;
}
static __device__ __forceinline__ bfpair split2(float f) {
    bfpair p;
    unsigned int u = __float_as_uint(f);
    p.hi = (unsigned short)(u >> 16);
    float r = f - __uint_as_float(u & 0xffff0000u);
    p.lo = (unsigned short)(__float_as_uint(r) >> 16);
    return p;
}
static __device__ __forceinline__ f32x4 MFMA(bf16x8 a, bf16x8 b, f32x4 c) {
    return __builtin_amdgcn_mfma_f32_16x16x32_bf16(a, b, c, 0, 0, 0);
}
static __device__ __forceinline__ float sigmoid_fast(float t) {
    return __builtin_amdgcn_rcpf(1.f + __expf(-t));
}

// ---- prep: Wbig = bf16([Wqkv(384); Wbr(8); zeros(8)]) [400][128]; Wp = bf16(Wproj)
__global__ __launch_bounds__(256) void prep_kernel(
    const float* __restrict__ Wqkv, const float* __restrict__ Wbr,
    const float* __restrict__ Wproj,
    unsigned short* __restrict__ Wbig, unsigned short* __restrict__ Wp)
{
    int i = blockIdx.x * 256 + threadIdx.x;
    if (i < 400 * 128) {
        int n = i >> 7, k = i & 127;
        float v = (n < 384) ? Wqkv[i] : (n < 392 ? Wbr[(n - 384) * 128 + k] : 0.f);
        Wbig[i] = f2bf_rn(v);
    } else {
        int j = i - 400 * 128;
        if (j < 128 * 128) Wp[j] = f2bf_rn(Wproj[j]);
    }
}

__global__ __launch_bounds__(256) void leaf_main(
    const float* __restrict__ x, const int* __restrict__ mask,
    const float* __restrict__ edge,
    const unsigned short* __restrict__ Wbig, const unsigned short* __restrict__ Wp,
    const float* __restrict__ bqkv, const float* __restrict__ bproj,
    const float* __restrict__ eg_w1, const float* __restrict__ eg_b1,
    const float* __restrict__ eg_w2, const float* __restrict__ eg_b2,
    const float* __restrict__ bbr, float* __restrict__ out)
{
    __shared__ unsigned short qhiS[16 * 136], qloS[16 * 136]; // q hi/lo (136-pad: 16B-aligned b128)
    __shared__ unsigned short kmS[16 * 136];                  // k (phases 1-3a) then x_mid (3-4)
    __shared__ unsigned short vtS[128 * 16];                  // [h*16+d][tok], 8-tok-chunk XOR swizzle
    __shared__ unsigned short ewS[8 * 256];                   // [h][q*16+k]
    __shared__ float logitS[16 * 20];                         // [q][k] padded
    __shared__ unsigned short gS[16 * 8];                     // [tok][h] bf16
    __shared__ float vbS[128];                                // v_blk [h*16+d]
    __shared__ unsigned short pS[4 * 16 * 16];                // per-wave P, chunk XOR swizzle
    // total 25344 B -> 6 blocks/CU

    const int bid  = blockIdx.x;
    const int tid  = threadIdx.x;
    const int wave = tid >> 6;
    const int lane = tid & 63;
    const int c15  = lane & 15;
    const int quad = lane >> 4;
    const bf16x8 zf = {0, 0, 0, 0, 0, 0, 0, 0};

    // ---- issue all independent global loads up front ----
    const int    mv = mask[(size_t)bid * 256 + tid];
    const float4 ev = *(const float4*)&edge[((size_t)bid * 256 + tid) * 4];

    // x A-fragments straight from global (8KB block; L1/L2-resident)
    const float* xr = x + (size_t)bid * 2048 + c15 * 128 + quad * 8;
    f32x4 xv[4][2];
    #pragma unroll
    for (int kk = 0; kk < 4; ++kk) {
        xv[kk][0] = *(const f32x4*)(xr + kk * 32);
        xv[kk][1] = *(const f32x4*)(xr + kk * 32 + 4);
    }

    // B prefetch depth 2: slot0 = q-tile wave, slot1 = q-tile wave+4
    bf16x8 Bt[2][4];
    const unsigned short* wbase = Wbig + c15 * 128 + quad * 8;
    {
        const unsigned short* w0 = wbase + (wave * 16) * 128;
        #pragma unroll
        for (int kk = 0; kk < 4; ++kk) Bt[0][kk] = *(const bf16x8*)(w0 + kk * 32);
        const unsigned short* w1 = wbase + ((wave + 4) * 16) * 128;
        #pragma unroll
        for (int kk = 0; kk < 4; ++kk) Bt[1][kk] = *(const bf16x8*)(w1 + kk * 32);
    }
    float bq[6];
    #pragma unroll
    for (int it = 0; it < 6; ++it) bq[it] = bqkv[(wave + it * 4) * 16 + c15];
    const float bgate = bbr[c15 & 7];

    // ---- split x into hi/lo A-fragments (frees xv) ----
    bf16x8 ah[4], al[4];
    #pragma unroll
    for (int kk = 0; kk < 4; ++kk) {
        #pragma unroll
        for (int j = 0; j < 8; ++j) {
            float f = (j < 4) ? xv[kk][0][j] : xv[kk][1][j - 4];
            bfpair p = split2(f);
            ah[kk][j] = (short)p.hi;
            al[kk][j] = (short)p.lo;
        }
    }

    // ---- edge-gate MLP (poly gelu: z is tiny, |z|<~1) + mask/logits ----
    {
        const int q = tid >> 4, k = tid & 15;
        int s = mv;
        s += __shfl_xor(s, 1); s += __shfl_xor(s, 2);
        s += __shfl_xor(s, 4); s += __shfl_xor(s, 8);
        float m = (float)mv;
        if (q == k && s < 1) m = 1.f;
        float bp0, bp1, bp2, bp3;
        if (q == k) { bp0 = bp1 = bp2 = 0.f; bp3 = 1.f; }
        else        { bp0 = ev.x; bp1 = ev.y; bp2 = ev.z; bp3 = ev.w; }
        logitS[q * 20 + k] = (m == 0.f) ? -INFINITY : bp3;
        float ew[8];
        #pragma unroll
        for (int h = 0; h < 8; ++h) ew[h] = eg_b2[h];
        #pragma unroll
        for (int j = 0; j < 16; ++j) {
            float z = eg_w1[j * 4 + 0] * bp0 + eg_w1[j * 4 + 1] * bp1 +
                      eg_w1[j * 4 + 2] * bp2 + eg_w1[j * 4 + 3] * bp3 + eg_b1[j];
            // gelu(z) = z*Phi(z); Phi ~= 0.5 + 0.3989423 z - 0.0664904 z^3 (|z|<1)
            float u  = z * z;
            float w  = __builtin_fmaf(-0.0664904f, u, 0.3989423f);
            float g  = z * __builtin_fmaf(z, w, 0.5f);
            #pragma unroll
            for (int h = 0; h < 8; ++h) ew[h] = __builtin_fmaf(eg_w2[h * 16 + j], g, ew[h]);
        }
        #pragma unroll
        for (int h = 0; h < 8; ++h)
            ewS[h * 256 + tid] = (m == 0.f) ? (unsigned short)0
                               : (unsigned short)(__float_as_uint(ew[h]) >> 16);
    }

    // ---- phase 1: qkv tiles (6 per wave) + gate (wave 0), rolling prefetch ----
    #pragma unroll
    for (int it = 0; it < 6; ++it) {
        f32x4 acc = {0.f, 0.f, 0.f, 0.f};
        #pragma unroll
        for (int kk = 0; kk < 4; ++kk) {
            acc = MFMA(ah[kk], Bt[it & 1][kk], acc);
            acc = MFMA(al[kk], Bt[it & 1][kk], acc);
        }
        if (it + 2 < 6 || (it + 2 == 6 && wave == 0)) {
            const int ntn = (it + 2 < 6) ? (wave + (it + 2) * 4) : 24;
            const unsigned short* wb = wbase + (ntn * 16) * 128;
            #pragma unroll
            for (int kk = 0; kk < 4; ++kk) Bt[it & 1][kk] = *(const bf16x8*)(wb + kk * 32);
        }
        const int col = (wave + (it & 1) * 4) * 16 + c15;
        const float bias = bq[it];
        if (it < 2) {            // q: hi/lo split
            #pragma unroll
            for (int r = 0; r < 4; ++r) {
                bfpair p = split2(acc[r] + bias);
                qhiS[(quad * 4 + r) * 136 + col] = p.hi;
                qloS[(quad * 4 + r) * 136 + col] = p.lo;
            }
        } else if (it < 4) {     // k: rounded
            #pragma unroll
            for (int r = 0; r < 4; ++r)
                kmS[(quad * 4 + r) * 136 + col] = f2bf_rn(acc[r] + bias);
        } else {                 // v: transposed, swizzled; block mean via shuffle
            us4 vw;
            #pragma unroll
            for (int r = 0; r < 4; ++r) vw[r] = f2bf_rn(acc[r] + bias);
            const int voff = col * 16 + (((quad >> 1) ^ (col & 1)) << 3) + ((quad & 1) << 2);
            *(us4*)&vtS[voff] = vw;
            float s = acc[0] + acc[1] + acc[2] + acc[3];
            s += __shfl_xor(s, 16);
            s += __shfl_xor(s, 32);
            if (lane < 16) vbS[col] = s * 0.0625f + bias;
        }
    }
    if (wave == 0) {             // gate tile
        f32x4 acc = {0.f, 0.f, 0.f, 0.f};
        #pragma unroll
        for (int kk = 0; kk < 4; ++kk) {
            acc = MFMA(ah[kk], Bt[0][kk], acc);
            acc = MFMA(al[kk], Bt[0][kk], acc);
        }
        if (c15 < 8) {
            #pragma unroll
            for (int r = 0; r < 4; ++r)
                gS[(quad * 4 + r) * 8 + c15] = f2bf_rn(sigmoid_fast(acc[r] + bgate));
        }
    }
    __syncthreads();   // barrier A: qkv/gate/MLP visible

    // ---- phase 3 prologue: hoist all khi/q frags to regs (frees kmS for x_mid) ----
    bf16x8 kh[2], qh[2], ql[2];
    #pragma unroll
    for (int hh = 0; hh < 2; ++hh) {
        const int h = 2 * wave + hh;
        const int fo = c15 * 136 + h * 16 + (quad & 1) * 8;
        kh[hh] = zf; qh[hh] = zf; ql[hh] = zf;
        if (quad < 2) {
            kh[hh] = *(const bf16x8*)&kmS[fo];
            qh[hh] = *(const bf16x8*)&qhiS[fo];
            ql[hh] = *(const bf16x8*)&qloS[fo];
        }
    }
    const f32x4 lg = *(const f32x4*)&logitS[c15 * 20 + quad * 4];
    us4 ea[2];
    #pragma unroll
    for (int hh = 0; hh < 2; ++hh)
        ea[hh] = *(const us4*)&ewS[(2 * wave + hh) * 256 + c15 * 16 + quad * 4];
    __syncthreads();   // barrier B: kmS free for x_mid writes

    // proj weights prefetch (latency hides under softmax/PV)
    bf16x8 Wt[2][4];
    float bpv[2];
    #pragma unroll
    for (int t = 0; t < 2; ++t) {
        const unsigned short* wp = Wp + ((wave + t * 4) * 16 + c15) * 128 + quad * 8;
        #pragma unroll
        for (int kk = 0; kk < 4; ++kk) Wt[t][kk] = *(const bf16x8*)(wp + kk * 32);
        bpv[t] = bproj[(wave + t * 4) * 16 + c15];
    }

    // ---- phase 3: two heads per wave, swapped QK^T ----
    #pragma unroll
    for (int hh = 0; hh < 2; ++hh) {
        const int h = 2 * wave + hh;
        f32x4 sc = {0.f, 0.f, 0.f, 0.f};
        sc = MFMA(kh[hh], qh[hh], sc);
        sc = MFMA(kh[hh], ql[hh], sc);
        float s0 = sc[0] * 0.25f + lg[0];
        float s1 = sc[1] * 0.25f + lg[1];
        float s2 = sc[2] * 0.25f + lg[2];
        float s3 = sc[3] * 0.25f + lg[3];
        float mx = fmaxf(fmaxf(s0, s1), fmaxf(s2, s3));
        mx = fmaxf(mx, __shfl_xor(mx, 16));
        mx = fmaxf(mx, __shfl_xor(mx, 32));
        float e0 = __expf(s0 - mx), e1 = __expf(s1 - mx);
        float e2 = __expf(s2 - mx), e3 = __expf(s3 - mx);
        float sm = (e0 + e1) + (e2 + e3);
        sm += __shfl_xor(sm, 16);
        sm += __shfl_xor(sm, 32);
        const float inv = __builtin_amdgcn_rcpf(sm);
        const float p0 = e0 * inv + bf2f(ea[hh][0]);
        const float p1 = e1 * inv + bf2f(ea[hh][1]);
        const float p2 = e2 * inv + bf2f(ea[hh][2]);
        const float p3 = e3 * inv + bf2f(ea[hh][3]);
        u32x2 pw;
        pw[0] = (unsigned int)f2bf_rn(p0) | ((unsigned int)f2bf_rn(p1) << 16);
        pw[1] = (unsigned int)f2bf_rn(p2) | ((unsigned int)f2bf_rn(p3) << 16);
        const int pwo = wave * 256 + c15 * 16 + (((quad >> 1) ^ (c15 & 1)) << 3) + ((quad & 1) << 2);
        *(u32x2*)&pS[pwo] = pw;

        bf16x8 pa = zf, vb = zf;
        if (quad < 2) {
            pa = *(const bf16x8*)&pS[wave * 256 + c15 * 16 + (((quad & 1) ^ (c15 & 1)) << 3)];
            const int vrow = h * 16 + c15;
            vb = *(const bf16x8*)&vtS[vrow * 16 + (((quad & 1) ^ (vrow & 1)) << 3)];
        }
        f32x4 xs = {0.f, 0.f, 0.f, 0.f};
        xs = MFMA(pa, vb, xs);
        const float vblk = vbS[h * 16 + c15];
        #pragma unroll
        for (int r = 0; r < 4; ++r) {
            const int tok = quad * 4 + r;
            float val = xs[r] + bf2f(gS[tok * 8 + h]) * vblk;
            kmS[tok * 136 + h * 16 + c15] = f2bf_rn(val);   // x_mid into k-space
        }
    }
    __syncthreads();   // barrier C: x_mid ready

    // ---- phase 4: output projection (2 col-tiles per wave) ----
    {
        bf16x8 mh[4];
        #pragma unroll
        for (int kk = 0; kk < 4; ++kk)
            mh[kk] = *(const bf16x8*)&kmS[c15 * 136 + kk * 32 + quad * 8];
        float* op = out + (size_t)bid * 2048;
        #pragma unroll
        for (int t = 0; t < 2; ++t) {
            f32x4 acc = {0.f, 0.f, 0.f, 0.f};
            #pragma unroll
            for (int kk = 0; kk < 4; ++kk) acc = MFMA(mh[kk], Wt[t][kk], acc);
            const int n0 = (wave + t * 4) * 16;
            #pragma unroll
            for (int r = 0; r < 4; ++r)
                op[(quad * 4 + r) * 128 + n0 + c15] = acc[r] + bpv[t];
        }
    }
}

extern "C" void kernel_launch(void* const* d_in, const int* in_sizes, int n_in,
                              void* d_out, int out_size, void* d_ws, size_t ws_size,
                              hipStream_t stream) {
    const float* x     = (const float*)d_in[0];
    const int*   amask = (const int*)  d_in[1];
    const float* edge  = (const float*)d_in[2];
    const float* Wqkv  = (const float*)d_in[3];
    const float* bqkv  = (const float*)d_in[4];
    const float* Wproj = (const float*)d_in[5];
    const float* bproj = (const float*)d_in[6];
    const float* eg_w1 = (const float*)d_in[7];
    const float* eg_b1 = (const float*)d_in[8];
    const float* eg_w2 = (const float*)d_in[9];
    const float* eg_b2 = (const float*)d_in[10];
    const float* Wbr   = (const float*)d_in[11];
    const float* bbr   = (const float*)d_in[12];
    float* outp = (float*)d_out;

    unsigned short* Wbig = (unsigned short*)d_ws;                      // 400*128 bf16
    unsigned short* Wp   = (unsigned short*)((char*)d_ws + 400 * 128 * 2);

    hipLaunchKernelGGL(prep_kernel, dim3(264), dim3(256), 0, stream,
                       Wqkv, Wbr, Wproj, Wbig, Wp);
    hipLaunchKernelGGL(leaf_main, dim3(8192), dim3(256), 0, stream,
                       x, amask, edge, Wbig, Wp, bqkv, bproj,
                       eg_w1, eg_b1, eg_w2, eg_b2, bbr, outp);
}

// Round 9
// 137.037 us; speedup vs baseline: 1.3841x; 1.1784x over previous
//
#include <hip/hip_runtime.h>
#include <hip/hip_bf16.h>
#include <math.h>

// B=4, NB=2048 -> 8192 leaf blocks of L=16 tokens x C=128; H=8 heads x D=16.
// 512 threads/block (8 waves), NITER=4 leaf blocks per workgroup (grid 2048).
// Wave w owns q/k/v col-tile w, head w, proj cols [w*16,w*16+16). Waves 0-3 run
// the edge MLP; wave 7 the block-node gate. Weight tiles roll through a depth-2
// register prefetch that wraps across iterations; x/mask/edge for block n+1 are
// issued at the top of iteration n.
typedef __attribute__((ext_vector_type(8))) short bf16x8;
typedef __attribute__((ext_vector_type(4))) float f32x4;
typedef __attribute__((ext_vector_type(4))) unsigned short us4;
typedef __attribute__((ext_vector_type(2))) unsigned int u32x2;

#define NITER 4

struct bfpair { unsigned short hi, lo; };

static __device__ __forceinline__ unsigned short f2bf_rn(float f) {
    union { __hip_bfloat16 h; unsigned short u; } cv;
    cv.h = __float2bfloat16(f);
    return cv.u;
}
static __device__ __forceinline__ float bf2f(unsigned short u) {
    union { unsigned int i; float f; } cv;
    cv.i = ((unsigned int)u) << 16;
    return cv.f;
}
static __device__ __forceinline__ bfpair split2(float f) {
    bfpair p;
    unsigned int u = __float_as_uint(f);
    p.hi = (unsigned short)(u >> 16);
    float r = f - __uint_as_float(u & 0xffff0000u);
    p.lo = (unsigned short)(__float_as_uint(r) >> 16);
    return p;
}
static __device__ __forceinline__ f32x4 MFMA(bf16x8 a, bf16x8 b, f32x4 c) {
    return __builtin_amdgcn_mfma_f32_16x16x32_bf16(a, b, c, 0, 0, 0);
}
static __device__ __forceinline__ float sigmoid_fast(float t) {
    return __builtin_amdgcn_rcpf(1.f + __expf(-t));
}

// ---- prep: Wbig = bf16([Wqkv(384); Wbr(8); zeros(8)]) [400][128]; Wp = bf16(Wproj)
__global__ __launch_bounds__(256) void prep_kernel(
    const float* __restrict__ Wqkv, const float* __restrict__ Wbr,
    const float* __restrict__ Wproj,
    unsigned short* __restrict__ Wbig, unsigned short* __restrict__ Wp)
{
    int i = blockIdx.x * 256 + threadIdx.x;
    if (i < 400 * 128) {
        int n = i >> 7, k = i & 127;
        float v = (n < 384) ? Wqkv[i] : (n < 392 ? Wbr[(n - 384) * 128 + k] : 0.f);
        Wbig[i] = f2bf_rn(v);
    } else {
        int j = i - 400 * 128;
        if (j < 128 * 128) Wp[j] = f2bf_rn(Wproj[j]);
    }
}

__global__ __launch_bounds__(512) void leaf_main(
    const float* __restrict__ x, const int* __restrict__ mask,
    const float* __restrict__ edge,
    const unsigned short* __restrict__ Wbig, const unsigned short* __restrict__ Wp,
    const float* __restrict__ bqkv, const float* __restrict__ bproj,
    const float* __restrict__ eg_w1, const float* __restrict__ eg_b1,
    const float* __restrict__ eg_w2, const float* __restrict__ eg_b2,
    const float* __restrict__ bbr, float* __restrict__ out)
{
    __shared__ unsigned short qhiS[16 * 136], qloS[16 * 136];  // q hi/lo (trunc split)
    __shared__ unsigned short khiS[16 * 136];                  // k rounded bf16
    __shared__ unsigned short vtS[128 * 24];                   // [h*16+d][tok(24 pad)]
    __shared__ unsigned short ewS[8 * 256];                    // [h][q*16+k]
    __shared__ float logitS[256];                              // [q*16+k]
    __shared__ unsigned short gS[16 * 8];                      // [tok][h] bf16
    __shared__ float vbS[128];                                 // v_blk [h*16+d]
    __shared__ union XU {                                      // x stage aliases P + x_mid
        struct { unsigned short xhi[16 * 128], xlo[16 * 128]; } a;
        struct { unsigned short p[8 * 16 * 24], mhi[16 * 136]; } b;
    } xu;
    // total ~35.6 KB -> 4 blocks/CU (8-wave blocks; 32-wave cap)

    const int tid  = threadIdx.x;
    const int lane = tid & 63;
    const int wave = tid >> 6;
    const int c15  = lane & 15;
    const int quad = lane >> 4;
    const bf16x8 zf = {0, 0, 0, 0, 0, 0, 0, 0};
    const int bid0 = blockIdx.x * NITER;

    // iteration-invariant constants
    const unsigned short* wbase = Wbig + c15 * 128 + quad * 8;
    const float bq0 = bqkv[wave * 16 + c15];
    const float bq1 = bqkv[128 + wave * 16 + c15];
    const float bq2 = bqkv[256 + wave * 16 + c15];
    const float bgate = bbr[c15 & 7];
    const float bpv = bproj[wave * 16 + c15];

    // ---- prologue loads for block bid0 ----
    int mv = 0;
    float4 evv = make_float4(0.f, 0.f, 0.f, 0.f);
    if (tid < 256) {
        mv  = mask[(size_t)bid0 * 256 + tid];
        evv = *(const float4*)&edge[((size_t)bid0 * 256 + tid) * 4];
    }
    float4 xv = ((const float4*)(x + (size_t)bid0 * 2048))[tid];

    // W rolling prefetch prologue: slot0 = q-tile(wave), slot1 = k-tile(8+wave)
    bf16x8 Bt[2][4];
    {
        const unsigned short* w0 = wbase + (wave * 16) * 128;
        #pragma unroll
        for (int kk = 0; kk < 4; ++kk) Bt[0][kk] = *(const bf16x8*)(w0 + kk * 32);
        const unsigned short* w1 = wbase + ((8 + wave) * 16) * 128;
        #pragma unroll
        for (int kk = 0; kk < 4; ++kk) Bt[1][kk] = *(const bf16x8*)(w1 + kk * 32);
    }

    // stage x for block 0 (trunc split, chunk-XOR swizzle)
    {
        int row = tid >> 5, c4 = tid & 31;
        int off = row * 128 + (((c4 >> 1) ^ (row & 7)) << 3) + ((c4 & 1) << 2);
        float f[4] = {xv.x, xv.y, xv.z, xv.w};
        us4 hi, lo;
        #pragma unroll
        for (int j = 0; j < 4; ++j) {
            bfpair p = split2(f[j]);
            hi[j] = p.hi;
            lo[j] = p.lo;
        }
        *(us4*)&xu.a.xhi[off] = hi;
        *(us4*)&xu.a.xlo[off] = lo;
    }
    __syncthreads();   // barrier A (iter 0): x staged

    #pragma unroll 1
    for (int it = 0; it < NITER; ++it) {
        const int bid = bid0 + it;
        const bool more = (it + 1 < NITER);

        // ---- issue next-block loads (complete during this iteration's compute) ----
        float4 xv_n = make_float4(0.f, 0.f, 0.f, 0.f);
        int mv_n = 0;
        float4 ev_n = make_float4(0.f, 0.f, 0.f, 0.f);
        if (more) {
            xv_n = ((const float4*)(x + (size_t)(bid + 1) * 2048))[tid];
            if (tid < 256) {
                mv_n = mask[(size_t)(bid + 1) * 256 + tid];
                ev_n = *(const float4*)&edge[((size_t)(bid + 1) * 256 + tid) * 4];
            }
        }

        // ---- edge-gate MLP (poly gelu) + mask/logits (waves 0-3) ----
        if (tid < 256) {
            const int q = tid >> 4, k = tid & 15;
            int s = mv;
            s += __shfl_xor(s, 1); s += __shfl_xor(s, 2);
            s += __shfl_xor(s, 4); s += __shfl_xor(s, 8);
            float m = (float)mv;
            if (q == k && s < 1) m = 1.f;
            float bp0, bp1, bp2, bp3;
            if (q == k) { bp0 = bp1 = bp2 = 0.f; bp3 = 1.f; }
            else        { bp0 = evv.x; bp1 = evv.y; bp2 = evv.z; bp3 = evv.w; }
            logitS[tid] = (m == 0.f) ? -INFINITY : bp3;
            float ew[8];
            #pragma unroll
            for (int h = 0; h < 8; ++h) ew[h] = eg_b2[h];
            #pragma unroll
            for (int j = 0; j < 16; ++j) {
                float z = eg_w1[j * 4 + 0] * bp0 + eg_w1[j * 4 + 1] * bp1 +
                          eg_w1[j * 4 + 2] * bp2 + eg_w1[j * 4 + 3] * bp3 + eg_b1[j];
                // gelu(z)=z*Phi(z); Phi ~= 0.5 + 0.3989423 z - 0.0664904 z^3 (|z|<1)
                float u = z * z;
                float w = __builtin_fmaf(-0.0664904f, u, 0.3989423f);
                float g = z * __builtin_fmaf(z, w, 0.5f);
                #pragma unroll
                for (int h = 0; h < 8; ++h) ew[h] = __builtin_fmaf(eg_w2[h * 16 + j], g, ew[h]);
            }
            #pragma unroll
            for (int h = 0; h < 8; ++h)
                ewS[h * 256 + tid] = (m == 0.f) ? (unsigned short)0
                                   : (unsigned short)(__float_as_uint(ew[h]) >> 16);
        }

        // ---- A-fragments from LDS (swizzled, conflict-free) ----
        bf16x8 ah[4], al[4];
        #pragma unroll
        for (int kk = 0; kk < 4; ++kk) {
            int off = c15 * 128 + (((kk * 4 + quad) ^ (c15 & 7)) << 3);
            ah[kk] = *(const bf16x8*)&xu.a.xhi[off];
            al[kk] = *(const bf16x8*)&xu.a.xlo[off];
        }

        const int colq = wave * 16 + c15;

        // ---- tile 0: q (hi/lo split) ----
        {
            f32x4 acc = {0.f, 0.f, 0.f, 0.f};
            #pragma unroll
            for (int kk = 0; kk < 4; ++kk) {
                acc = MFMA(ah[kk], Bt[0][kk], acc);
                acc = MFMA(al[kk], Bt[0][kk], acc);
            }
            // prefetch v-tile into slot 0
            const unsigned short* w2 = wbase + ((16 + wave) * 16) * 128;
            #pragma unroll
            for (int kk = 0; kk < 4; ++kk) Bt[0][kk] = *(const bf16x8*)(w2 + kk * 32);
            #pragma unroll
            for (int r = 0; r < 4; ++r) {
                bfpair p = split2(acc[r] + bq0);
                qhiS[(quad * 4 + r) * 136 + colq] = p.hi;
                qloS[(quad * 4 + r) * 136 + colq] = p.lo;
            }
        }

        // ---- tile 1: k (rounded) ----
        {
            f32x4 acc = {0.f, 0.f, 0.f, 0.f};
            #pragma unroll
            for (int kk = 0; kk < 4; ++kk) {
                acc = MFMA(ah[kk], Bt[1][kk], acc);
                acc = MFMA(al[kk], Bt[1][kk], acc);
            }
            if (wave == 7) {   // prefetch gate tile into slot 1
                const unsigned short* w3 = wbase + 384 * 128;
                #pragma unroll
                for (int kk = 0; kk < 4; ++kk) Bt[1][kk] = *(const bf16x8*)(w3 + kk * 32);
            }
            #pragma unroll
            for (int r = 0; r < 4; ++r)
                khiS[(quad * 4 + r) * 136 + colq] = f2bf_rn(acc[r] + bq1);
        }

        // ---- tile 2: v (transposed; block mean via shuffle) ----
        {
            f32x4 acc = {0.f, 0.f, 0.f, 0.f};
            #pragma unroll
            for (int kk = 0; kk < 4; ++kk) {
                acc = MFMA(ah[kk], Bt[0][kk], acc);
                acc = MFMA(al[kk], Bt[0][kk], acc);
            }
            // wrap prefetch: next iteration's q-tile into slot 0
            const unsigned short* w0 = wbase + (wave * 16) * 128;
            #pragma unroll
            for (int kk = 0; kk < 4; ++kk) Bt[0][kk] = *(const bf16x8*)(w0 + kk * 32);
            #pragma unroll
            for (int r = 0; r < 4; ++r)
                vtS[colq * 24 + quad * 4 + r] = f2bf_rn(acc[r] + bq2);
            float s = acc[0] + acc[1] + acc[2] + acc[3];
            s += __shfl_xor(s, 16);
            s += __shfl_xor(s, 32);
            if (lane < 16) vbS[colq] = s * 0.0625f + bq2;
        }

        // ---- tile 3: block-node gate (wave 7) ----
        if (wave == 7) {
            f32x4 acc = {0.f, 0.f, 0.f, 0.f};
            #pragma unroll
            for (int kk = 0; kk < 4; ++kk) {
                acc = MFMA(ah[kk], Bt[1][kk], acc);
                acc = MFMA(al[kk], Bt[1][kk], acc);
            }
            if (c15 < 8) {
                #pragma unroll
                for (int r = 0; r < 4; ++r)
                    gS[(quad * 4 + r) * 8 + c15] = f2bf_rn(sigmoid_fast(acc[r] + bgate));
            }
        }
        // wrap prefetch: next iteration's k-tile into slot 1 (all waves)
        {
            const unsigned short* w1 = wbase + ((8 + wave) * 16) * 128;
            #pragma unroll
            for (int kk = 0; kk < 4; ++kk) Bt[1][kk] = *(const bf16x8*)(w1 + kk * 32);
        }
        __syncthreads();   // barrier B: qkv/gate/MLP visible; x-stage LDS dead

        // proj weights prefetch (latency hides under attention)
        bf16x8 Wt[4];
        {
            const unsigned short* wp = Wp + (wave * 16 + c15) * 128 + quad * 8;
            #pragma unroll
            for (int kk = 0; kk < 4; ++kk) Wt[kk] = *(const bf16x8*)(wp + kk * 32);
        }

        // ---- attention, swapped QK^T (head h = wave) ----
        {
            const int h = wave;
            const int fo = c15 * 136 + h * 16 + (quad & 1) * 8;
            bf16x8 kh_ = zf, qh_ = zf, ql_ = zf;
            if (quad < 2) {
                kh_ = *(const bf16x8*)&khiS[fo];
                qh_ = *(const bf16x8*)&qhiS[fo];
                ql_ = *(const bf16x8*)&qloS[fo];
            }
            f32x4 sc = {0.f, 0.f, 0.f, 0.f};
            sc = MFMA(kh_, qh_, sc);
            sc = MFMA(kh_, ql_, sc);
            const f32x4 lg = *(const f32x4*)&logitS[c15 * 16 + quad * 4];
            const us4 ew4 = *(const us4*)&ewS[h * 256 + c15 * 16 + quad * 4];
            float s0 = sc[0] * 0.25f + lg[0];
            float s1 = sc[1] * 0.25f + lg[1];
            float s2 = sc[2] * 0.25f + lg[2];
            float s3 = sc[3] * 0.25f + lg[3];
            float mx = fmaxf(fmaxf(s0, s1), fmaxf(s2, s3));
            mx = fmaxf(mx, __shfl_xor(mx, 16));
            mx = fmaxf(mx, __shfl_xor(mx, 32));
            float e0 = __expf(s0 - mx), e1 = __expf(s1 - mx);
            float e2 = __expf(s2 - mx), e3 = __expf(s3 - mx);
            float sm = (e0 + e1) + (e2 + e3);
            sm += __shfl_xor(sm, 16);
            sm += __shfl_xor(sm, 32);
            const float inv = __builtin_amdgcn_rcpf(sm);
            const float p0 = e0 * inv + bf2f(ew4[0]);
            const float p1 = e1 * inv + bf2f(ew4[1]);
            const float p2 = e2 * inv + bf2f(ew4[2]);
            const float p3 = e3 * inv + bf2f(ew4[3]);
            u32x2 pw;
            pw[0] = (unsigned int)f2bf_rn(p0) | ((unsigned int)f2bf_rn(p1) << 16);
            pw[1] = (unsigned int)f2bf_rn(p2) | ((unsigned int)f2bf_rn(p3) << 16);
            *(u32x2*)&xu.b.p[wave * 384 + c15 * 24 + quad * 4] = pw;

            bf16x8 pa = zf, vb = zf;
            if (quad < 2) {
                pa = *(const bf16x8*)&xu.b.p[wave * 384 + c15 * 24 + (quad & 1) * 8];
                vb = *(const bf16x8*)&vtS[(h * 16 + c15) * 24 + (quad & 1) * 8];
            }
            f32x4 xs = {0.f, 0.f, 0.f, 0.f};
            xs = MFMA(pa, vb, xs);
            const float vblk = vbS[h * 16 + c15];
            #pragma unroll
            for (int r = 0; r < 4; ++r) {
                const int tok = quad * 4 + r;
                float val = xs[r] + bf2f(gS[tok * 8 + h]) * vblk;
                xu.b.mhi[tok * 136 + h * 16 + c15] = f2bf_rn(val);
            }
        }
        __syncthreads();   // barrier C: x_mid ready

        // ---- output projection (one 16-col tile per wave) ----
        {
            bf16x8 mh[4];
            #pragma unroll
            for (int kk = 0; kk < 4; ++kk)
                mh[kk] = *(const bf16x8*)&xu.b.mhi[c15 * 136 + kk * 32 + quad * 8];
            f32x4 acc = {0.f, 0.f, 0.f, 0.f};
            #pragma unroll
            for (int kk = 0; kk < 4; ++kk) acc = MFMA(mh[kk], Wt[kk], acc);
            float* op = out + (size_t)bid * 2048;
            #pragma unroll
            for (int r = 0; r < 4; ++r)
                op[(quad * 4 + r) * 128 + wave * 16 + c15] = acc[r] + bpv;
        }

        // ---- stage next block's x; rotate mask/edge ----
        if (more) {
            __syncthreads();   // barrier D: proj reads of xu.b done
            int row = tid >> 5, c4 = tid & 31;
            int off = row * 128 + (((c4 >> 1) ^ (row & 7)) << 3) + ((c4 & 1) << 2);
            float f[4] = {xv_n.x, xv_n.y, xv_n.z, xv_n.w};
            us4 hi, lo;
            #pragma unroll
            for (int j = 0; j < 4; ++j) {
                bfpair p = split2(f[j]);
                hi[j] = p.hi;
                lo[j] = p.lo;
            }
            *(us4*)&xu.a.xhi[off] = hi;
            *(us4*)&xu.a.xlo[off] = lo;
            mv = mv_n;
            evv = ev_n;
            __syncthreads();   // barrier A for next iteration
        }
    }
}

extern "C" void kernel_launch(void* const* d_in, const int* in_sizes, int n_in,
                              void* d_out, int out_size, void* d_ws, size_t ws_size,
                              hipStream_t stream) {
    const float* x     = (const float*)d_in[0];
    const int*   amask = (const int*)  d_in[1];
    const float* edge  = (const float*)d_in[2];
    const float* Wqkv  = (const float*)d_in[3];
    const float* bqkv  = (const float*)d_in[4];
    const float* Wproj = (const float*)d_in[5];
    const float* bproj = (const float*)d_in[6];
    const float* eg_w1 = (const float*)d_in[7];
    const float* eg_b1 = (const float*)d_in[8];
    const float* eg_w2 = (const float*)d_in[9];
    const float* eg_b2 = (const float*)d_in[10];
    const float* Wbr   = (const float*)d_in[11];
    const float* bbr   = (const float*)d_in[12];
    float* outp = (float*)d_out;

    unsigned short* Wbig = (unsigned short*)d_ws;                      // 400*128 bf16
    unsigned short* Wp   = (unsigned short*)((char*)d_ws + 400 * 128 * 2);

    hipLaunchKernelGGL(prep_kernel, dim3(264), dim3(256), 0, stream,
                       Wqkv, Wbr, Wproj, Wbig, Wp);
    hipLaunchKernelGGL(leaf_main, dim3(8192 / NITER), dim3(512), 0, stream,
                       x, amask, edge, Wbig, Wp, bqkv, bproj,
                       eg_w1, eg_b1, eg_w2, eg_b2, bbr, outp);
}